// Round 1
// baseline (292.673 us; speedup 1.0000x reference)
//
#include <hip/hip_runtime.h>
#include <hip/hip_bf16.h>

// ---------------------------------------------------------------------------
// GAT 2-layer forward on MI355X (gfx950).
// R8: aggregate rework — (a) 16B half8 gather loads; wave processes GRP edges
//     per iteration (2 for H*C=256, 4 for H*C=128) with cross-group shfl_xor
//     reduce at the end; (b) {src,weight} packed as float2 in LDS (single
//     ds_read_b64 per edge/lane); (c) 4 dsts per 256-thread block, one per
//     wave, private LDS slices, no s_barrier (intra-wave DS ops are ordered;
//     wave_barrier pins the compiler) -> grid 50000 -> 12500, off the
//     dispatch-rate ceiling.
// R7: rank-trick atomic-free CSR scatter fused into gemm1 as dedicated blocks.
// fp16 intermediates, MFMA f16 GEMMs + fused att-logit epilogue, softmax
// shift-invariance (no max pass), end-normalization (no denom pass).
// ---------------------------------------------------------------------------

typedef _Float16 half8v __attribute__((ext_vector_type(8)));
typedef _Float16 half4v __attribute__((ext_vector_type(4)));
typedef _Float16 half2v __attribute__((ext_vector_type(2)));
typedef float f32x4 __attribute__((ext_vector_type(4)));

// --- MFMA GEMM + fused attention logits (+ block-specialized scatter) ------
// GEMM blocks: C[M, H*128](f16) = A[M,K] @ B[H*128,K]^T; a_s/a_d from fp32
// accumulators in the epilogue. 128x128 tile, BK=32, 4 waves.
// Scatter blocks (bid >= GB*H): atomic-free CSR scatter via precomputed rank.
// 1D grid; bid < GB*H: m0=(bid%GB)*128, head=bid/GB.

template <typename TA, int H, bool SCATTER>
__global__ __launch_bounds__(256) void gemm_att_kernel(
    const TA* __restrict__ A,        // [M,K] row-major (float or _Float16)
    const float* __restrict__ B,     // [H*128, K] row-major fp32 weights
    _Float16* __restrict__ C,        // [M, H*128] fp16 out
    const float* __restrict__ att_s, // [H*128]
    const float* __restrict__ att_d, // [H*128]
    float* __restrict__ a_s,         // [M*H]
    float* __restrict__ a_d,         // [M*H]
    int M, int K, int GB,            // GB = GEMM blocks per head
    const int* __restrict__ esrc, const int* __restrict__ edst,
    const int* __restrict__ rank, const int* __restrict__ csr_off,
    int* __restrict__ csr_src, int E, int nScatBlk)
{
    constexpr int BM = 128, BK = 32, LDA = 40;   // 40 f16 = 80 B = 5*16 B
    constexpr int NCOL = H * 128;
    __shared__ _Float16 Ah[BM * LDA];
    __shared__ _Float16 Bh[BM * LDA];
    __shared__ float red[2][2][64][2];           // [wm][wn][row][s|d]

    const int tid = threadIdx.x;
    const int bid = blockIdx.x;

    if constexpr (SCATTER) {
        if (bid >= GB * H) {
            // ---- dedicated scatter block: no atomics, no dependencies ----
            const int sbid = bid - GB * H;
            const int nq = (E + 3) >> 2;
            for (int q = sbid * 256 + tid; q < nq; q += nScatBlk * 256) {
                const int e4 = q * 4;
                if (e4 + 3 < E) {
                    const int4 sv = *reinterpret_cast<const int4*>(esrc + e4);
                    const int4 dv = *reinterpret_cast<const int4*>(edst + e4);
                    const int4 rv = *reinterpret_cast<const int4*>(rank + e4);
                    csr_src[csr_off[dv.x] + 1 + rv.x] = sv.x;
                    csr_src[csr_off[dv.y] + 1 + rv.y] = sv.y;
                    csr_src[csr_off[dv.z] + 1 + rv.z] = sv.z;
                    csr_src[csr_off[dv.w] + 1 + rv.w] = sv.w;
                } else {
                    for (int k = e4; k < E; ++k)
                        csr_src[csr_off[edst[k]] + 1 + rank[k]] = esrc[k];
                }
            }
            return;
        }
    }

    const int m0 = (bid % GB) * BM;
    const int by = bid / GB;                     // head
    const int n0 = by * 128;
    const int w  = tid >> 6;
    const int l  = tid & 63;
    const int wm = (w >> 1) * 64;
    const int wn = (w & 1) * 64;
    const int lr = l & 15;
    const int lq = l >> 4;

    f32x4 acc[4][4] = {};

    for (int k0 = 0; k0 < K; k0 += BK) {
        if constexpr (__is_same(TA, float)) {
#pragma unroll
            for (int it = 0; it < 4; ++it) {
                const int row = (tid >> 3) + it * 32;
                const int gm  = min(m0 + row, M - 1);
                const int c4  = (tid & 7) * 4;
                float4 v = *reinterpret_cast<const float4*>(A + (long)gm * K + k0 + c4);
                half4v o = { (_Float16)v.x, (_Float16)v.y, (_Float16)v.z, (_Float16)v.w };
                *reinterpret_cast<half4v*>(&Ah[row * LDA + c4]) = o;
            }
        } else {
#pragma unroll
            for (int it = 0; it < 2; ++it) {
                const int row = (tid >> 2) + it * 64;
                const int gm  = min(m0 + row, M - 1);
                const int c8  = (tid & 3) * 8;
                float4 v = *reinterpret_cast<const float4*>((const char*)A + ((long)gm * K + k0 + c8) * 2);
                *reinterpret_cast<float4*>(&Ah[row * LDA + c8]) = v;
            }
        }
#pragma unroll
        for (int it = 0; it < 4; ++it) {
            const int row = (tid >> 3) + it * 32;
            const int c4  = (tid & 7) * 4;
            float4 v = *reinterpret_cast<const float4*>(B + (long)(n0 + row) * K + k0 + c4);
            half4v o = { (_Float16)v.x, (_Float16)v.y, (_Float16)v.z, (_Float16)v.w };
            *reinterpret_cast<half4v*>(&Bh[row * LDA + c4]) = o;
        }
        __syncthreads();

        half8v af[4], bf[4];
#pragma unroll
        for (int i = 0; i < 4; ++i)
            af[i] = *reinterpret_cast<const half8v*>(&Ah[(wm + i * 16 + lr) * LDA + lq * 8]);
#pragma unroll
        for (int j = 0; j < 4; ++j)
            bf[j] = *reinterpret_cast<const half8v*>(&Bh[(wn + j * 16 + lr) * LDA + lq * 8]);
#pragma unroll
        for (int i = 0; i < 4; ++i)
#pragma unroll
            for (int j = 0; j < 4; ++j)
                acc[i][j] = __builtin_amdgcn_mfma_f32_16x16x32_f16(af[i], bf[j], acc[i][j], 0, 0, 0);
        __syncthreads();
    }

    // ---- store C ----
#pragma unroll
    for (int i = 0; i < 4; ++i) {
        const int gm_base = m0 + wm + i * 16 + lq * 4;
#pragma unroll
        for (int r = 0; r < 4; ++r) {
            const int gm = gm_base + r;
            if (gm < M) {
#pragma unroll
                for (int j = 0; j < 4; ++j)
                    C[(long)gm * NCOL + n0 + wn + j * 16 + lr] = (_Float16)acc[i][j][r];
            }
        }
    }

    // ---- fused attention logits ----
    float asv[4], adv[4];
#pragma unroll
    for (int j = 0; j < 4; ++j) {
        asv[j] = att_s[n0 + wn + j * 16 + lr];
        adv[j] = att_d[n0 + wn + j * 16 + lr];
    }
    float ps[4][4] = {}, pd[4][4] = {};
#pragma unroll
    for (int i = 0; i < 4; ++i)
#pragma unroll
        for (int j = 0; j < 4; ++j)
#pragma unroll
            for (int r = 0; r < 4; ++r) {
                ps[i][r] += acc[i][j][r] * asv[j];
                pd[i][r] += acc[i][j][r] * adv[j];
            }
#pragma unroll
    for (int o = 1; o < 16; o <<= 1)
#pragma unroll
        for (int i = 0; i < 4; ++i)
#pragma unroll
            for (int r = 0; r < 4; ++r) {
                ps[i][r] += __shfl_xor(ps[i][r], o, 64);
                pd[i][r] += __shfl_xor(pd[i][r], o, 64);
            }
    if (lr == 0) {
#pragma unroll
        for (int i = 0; i < 4; ++i)
#pragma unroll
            for (int r = 0; r < 4; ++r) {
                const int row = i * 16 + lq * 4 + r;
                red[wm >> 6][wn >> 6][row][0] = ps[i][r];
                red[wm >> 6][wn >> 6][row][1] = pd[i][r];
            }
    }
    __syncthreads();
    if (wn == 0) {                       // waves 0 and 2 cover wm = 0, 64
        const int row = l;
        const int gm = m0 + wm + row;
        if (gm < M) {
            const int wi = wm >> 6;
            a_s[(long)gm * H + by] = red[wi][0][row][0] + red[wi][1][row][0];
            a_d[(long)gm * H + by] = red[wi][0][row][1] + red[wi][1][row][1];
        }
    }
}

// --- CSR build --------------------------------------------------------------

// count + rank: rank[e] = position of edge e within its dst's neighborhood
__global__ void count_kernel(const int* __restrict__ dst, int* __restrict__ deg,
                             int* __restrict__ rank, int E)
{
    const int tid = blockIdx.x * blockDim.x + threadIdx.x;
    const int e4 = tid * 4;
    if (e4 + 3 < E) {
        const int4 d = *reinterpret_cast<const int4*>(dst + e4);
        int4 r;
        r.x = atomicAdd(&deg[d.x], 1);
        r.y = atomicAdd(&deg[d.y], 1);
        r.z = atomicAdd(&deg[d.z], 1);
        r.w = atomicAdd(&deg[d.w], 1);
        *reinterpret_cast<int4*>(rank + e4) = r;
    } else if (e4 < E) {
        for (int k = e4; k < E; ++k) rank[k] = atomicAdd(&deg[dst[k]], 1);
    }
}

// per-block exclusive scan of (deg[i]+1), 1024 elems/block, int4/thread
__global__ __launch_bounds__(256) void block_scan_kernel(
    const int* __restrict__ deg, int* __restrict__ pre, int* __restrict__ blk, int n)
{
    __shared__ int s[256];
    const int t = threadIdx.x;
    const int base = blockIdx.x * 1024 + t * 4;
    int4 d = make_int4(-1, -1, -1, -1);   // +1 -> 0 contribution OOB
    if (base + 3 < n) d = *reinterpret_cast<const int4*>(deg + base);
    else {
        if (base + 0 < n) d.x = deg[base + 0];
        if (base + 1 < n) d.y = deg[base + 1];
        if (base + 2 < n) d.z = deg[base + 2];
        if (base + 3 < n) d.w = deg[base + 3];
    }
    const int v0 = d.x + 1, v1 = d.y + 1, v2 = d.z + 1, v3 = d.w + 1;
    s[t] = v0 + v1 + v2 + v3;
    __syncthreads();
#pragma unroll
    for (int o = 1; o < 256; o <<= 1) {
        int val = 0;
        if (t >= o) val = s[t - o];
        __syncthreads();
        s[t] += val;
        __syncthreads();
    }
    int run = (t == 0) ? 0 : s[t - 1];
    int4 o4;
    o4.x = run; run += v0;
    o4.y = run; run += v1;
    o4.z = run; run += v2;
    o4.w = run; run += v3;
    if (base + 3 < n) *reinterpret_cast<int4*>(pre + base) = o4;
    else {
        if (base + 0 < n) pre[base + 0] = o4.x;
        if (base + 1 < n) pre[base + 1] = o4.y;
        if (base + 2 < n) pre[base + 2] = o4.z;
        if (base + 3 < n) pre[base + 3] = o4.w;
    }
    if (t == 255) blk[blockIdx.x] = s[255];
}

// finalize: add prefix of block totals; emit csr_off; pre-place self-loop at
// row start (csr_src[off] = node).
__global__ __launch_bounds__(256) void finalize_scan_kernel(
    const int* __restrict__ pre, const int* __restrict__ blk,
    int* __restrict__ off, int* __restrict__ csr_src, int n, int nvb)
{
    __shared__ int s_add;
    const int vb = blockIdx.x;
    const int t  = threadIdx.x;
    if (t < 64) {
        int v = (t < vb) ? blk[t] : 0;    // nvb <= 64
#pragma unroll
        for (int o = 32; o > 0; o >>= 1) v += __shfl_xor(v, o, 64);
        if (t == 0) s_add = v;
    }
    __syncthreads();
    const int add = s_add;
    const int base = vb * 1024 + t * 4;
    if (base + 3 < n) {
        int4 p = *reinterpret_cast<const int4*>(pre + base);
        p.x += add; p.y += add; p.z += add; p.w += add;
        *reinterpret_cast<int4*>(off + base) = p;
        csr_src[p.x] = base + 0;
        csr_src[p.y] = base + 1;
        csr_src[p.z] = base + 2;
        csr_src[p.w] = base + 3;
    } else {
#pragma unroll
        for (int k = 0; k < 4; ++k)
            if (base + k < n) {
                const int v = pre[base + k] + add;
                off[base + k] = v;
                csr_src[v] = base + k;
            }
    }
    if (vb == nvb - 1 && t == 0) off[n] = add + blk[vb];
}

// --- pull-based aggregation (R8: grouped 16B gather, 4 dsts/block) ---------
// One wave per dst. Wave splits into GRP groups of LPE lanes; group g handles
// edge jj+g each iteration with half8 (16B) loads. {src, w} packed as float2
// in LDS (1x ds_read_b64 per edge/lane). No block barrier: each wave owns a
// private LDS slice; intra-wave DS ops are program-ordered (wave_barrier
// pins compiler scheduling). Cross-group shfl_xor reduce at the end.

template <int H, int C, bool RELU, typename TOUT>
__global__ __launch_bounds__(256) void aggregate_kernel(
    const int* __restrict__ csr_off,
    const int* __restrict__ csr_src,
    const _Float16* __restrict__ h,  // [N, H*C] fp16
    const float* __restrict__ a_s,   // [N, H]
    const float* __restrict__ a_d,   // [N, H]
    const float* __restrict__ bias,  // [H*C]
    TOUT* __restrict__ out,          // [N, H*C]
    int N)
{
    constexpr int VPT = 8;
    constexpr int HC  = H * C;
    constexpr int LPE = HC / VPT;        // lanes per edge: 32 (L1), 16 (L2)
    constexpr int GRP = 64 / LPE;        // edges per wave-iter: 2 (L1), 4 (L2)

    const int w = threadIdx.x >> 6;      // wave in block -> dst slot
    const int l = threadIdx.x & 63;
    const int d = blockIdx.x * 4 + w;
    if (d >= N) return;

    const int g   = l / LPE;             // edge group
    const int col = (l % LPE) * VPT;     // feature column base
    const int hh  = col / C;             // head of this lane's columns

    __shared__ float2 s_sw[4][64][H];    // [wave][edge][head] = {src, w}

    const int beg = csr_off[d];
    const int end = csr_off[d + 1];

    float ad0 = 0.f, ad1 = 0.f;
    if constexpr (H == 2) {
        const float2 t2 = *reinterpret_cast<const float2*>(a_d + (long)d * 2);
        ad0 = t2.x; ad1 = t2.y;
    } else {
        ad0 = a_d[d];
    }

    float acc[VPT] = {};
    float wsum = 0.f;

    for (int base = beg; base < end; base += 64) {
        const int len  = min(64, end - base);
        const int lenp = (len + GRP - 1) & ~(GRP - 1);   // pad to GRP
        if (l < len) {
            const int s = csr_src[base + l];
            if constexpr (H == 2) {
                const float2 sv = *reinterpret_cast<const float2*>(a_s + (long)s * 2);
                float lg0 = sv.x + ad0; lg0 = lg0 > 0.f ? lg0 : 0.2f * lg0;
                float lg1 = sv.y + ad1; lg1 = lg1 > 0.f ? lg1 : 0.2f * lg1;
                s_sw[w][l][0] = make_float2(__int_as_float(s), __expf(lg0));
                s_sw[w][l][1] = make_float2(__int_as_float(s), __expf(lg1));
            } else {
                float lg = a_s[s] + ad0; lg = lg > 0.f ? lg : 0.2f * lg;
                s_sw[w][l][0] = make_float2(__int_as_float(s), __expf(lg));
            }
        } else if (l < lenp) {           // padding: weight 0, safe src = d
#pragma unroll
            for (int h2 = 0; h2 < H; ++h2)
                s_sw[w][l][h2] = make_float2(__int_as_float(d), 0.f);
        }
        __builtin_amdgcn_wave_barrier();
#pragma unroll 2
        for (int jj = 0; jj < lenp; jj += GRP) {
            const float2 sw = s_sw[w][jj + g][hh];
            const int    s  = __float_as_int(sw.x);
            const float  wt = sw.y;
            const half8v hv = *reinterpret_cast<const half8v*>(
                h + (long)s * HC + col);
#pragma unroll
            for (int k = 0; k < VPT; ++k)
                acc[k] += wt * (float)hv[k];
            wsum += wt;
        }
        __builtin_amdgcn_wave_barrier();
    }

    // cross-group reduce (groups cover disjoint edges of the same columns)
#pragma unroll
    for (int o = LPE; o < 64; o <<= 1) {
#pragma unroll
        for (int k = 0; k < VPT; ++k) acc[k] += __shfl_xor(acc[k], o, 64);
        wsum += __shfl_xor(wsum, o, 64);
    }

    if (g == 0) {
        const float inv = 1.f / wsum;
        float r[VPT];
#pragma unroll
        for (int k = 0; k < VPT; ++k) {
            r[k] = acc[k] * inv + bias[col + k];
            if (RELU) r[k] = r[k] > 0.f ? r[k] : 0.f;
        }
        if constexpr (__is_same(TOUT, _Float16)) {
            half8v ov;
#pragma unroll
            for (int k = 0; k < VPT; ++k) ov[k] = (_Float16)r[k];
            *reinterpret_cast<half8v*>(out + (long)d * HC + col) = ov;
        } else {
            f32x4 o0 = { r[0], r[1], r[2], r[3] };
            f32x4 o1 = { r[4], r[5], r[6], r[7] };
            *reinterpret_cast<f32x4*>(out + (long)d * HC + col)     = o0;
            *reinterpret_cast<f32x4*>(out + (long)d * HC + col + 4) = o1;
        }
    }
}

// ---------------------------------------------------------------------------

extern "C" void kernel_launch(void* const* d_in, const int* in_sizes, int n_in,
                              void* d_out, int out_size, void* d_ws, size_t ws_size,
                              hipStream_t stream)
{
    const float* x    = (const float*)d_in[0];
    const int*   eidx = (const int*)d_in[1];
    const float* W1   = (const float*)d_in[2];
    const float* as1  = (const float*)d_in[3];
    const float* ad1  = (const float*)d_in[4];
    const float* b1   = (const float*)d_in[5];
    const float* W2   = (const float*)d_in[6];
    const float* as2  = (const float*)d_in[7];
    const float* ad2  = (const float*)d_in[8];
    const float* b2   = (const float*)d_in[9];
    float* out = (float*)d_out;

    const int IN_FEATS = 256;
    const int N = in_sizes[0] / IN_FEATS;    // 50000
    const int E = in_sizes[1] / 2;           // 800000

    const int* esrc = eidx;
    const int* edst = eidx + E;

    size_t off = 0;
    auto alloc = [&](size_t bytes) -> void* {
        void* p = (char*)d_ws + off;
        off += (bytes + 255) & ~(size_t)255;
        return p;
    };
    _Float16* h1h   = (_Float16*)alloc((size_t)N * 256 * 2);
    _Float16* o1h   = (_Float16*)alloc((size_t)N * 256 * 2);
    _Float16* h2h   = (_Float16*)alloc((size_t)N * 128 * 2);
    float* a1s      = (float*)alloc((size_t)N * 2 * 4);
    float* a1d      = (float*)alloc((size_t)N * 2 * 4);
    float* a2s      = (float*)alloc((size_t)N * 4);
    float* a2d      = (float*)alloc((size_t)N * 4);
    int*   deg      = (int*)alloc((size_t)N * 4);
    int*   pre      = (int*)alloc((size_t)N * 4);
    int*   rank     = (int*)alloc((size_t)E * 4);
    int*   csr_off  = (int*)alloc((size_t)(N + 1) * 4);
    int*   csr_src  = (int*)alloc((size_t)(E + N) * 4);
    int*   blk      = (int*)alloc(64 * 4);

    const int nvb = (N + 1023) / 1024;    // 49 <= 64

    // --- CSR offsets + ranks (scatter itself fused into gemm1) ---
    hipMemsetAsync(deg, 0, (size_t)N * 4, stream);
    count_kernel<<<((E + 3) / 4 + 255) / 256, 256, 0, stream>>>(edst, deg, rank, E);
    block_scan_kernel<<<nvb, 256, 0, stream>>>(deg, pre, blk, N);
    finalize_scan_kernel<<<nvb, 256, 0, stream>>>(pre, blk, csr_off, csr_src, N, nvb);

    // --- layer 1: GEMM(784 blocks) + dedicated scatter blocks(192) ---
    {
        const int GB = (N + 127) / 128;      // 392
        const int nScat = 192;               // 784 + 192 = 976 <= 1024 co-res
        gemm_att_kernel<float, 2, true><<<GB * 2 + nScat, 256, 0, stream>>>(
            x, W1, h1h, as1, ad1, a1s, a1d, N, 256, GB,
            esrc, edst, rank, csr_off, csr_src, E, nScat);
    }
    aggregate_kernel<2, 128, true, _Float16><<<(N + 3) / 4, 256, 0, stream>>>(
        csr_off, csr_src, h1h, a1s, a1d, b1, o1h, N);

    // --- layer 2: GEMM + att logits, then aggregate ---
    {
        const int GB = (N + 127) / 128;
        gemm_att_kernel<_Float16, 1, false><<<GB, 256, 0, stream>>>(
            o1h, W2, h2h, as2, ad2, a2s, a2d, N, 256, GB,
            nullptr, nullptr, nullptr, nullptr, nullptr, 0, 0);
    }
    aggregate_kernel<1, 128, false, float><<<(N + 3) / 4, 256, 0, stream>>>(
        csr_off, csr_src, h2h, a2s, a2d, b2, out, N);
}